// Round 18
// baseline (93.706 us; speedup 1.0000x reference)
//
#include <hip/hip_runtime.h>
#include <hip/hip_bf16.h>

// Bloom MLP fused: h=X@W1^T+b1; g=gelu_tanh(h); out=g@W2^T+b2+residual
// X:[262144,64] f32, W1:[256,64], W2:[64,256], out:[262144,64] f32.
//
// Round 18: zero-LDS, zero-barrier, max-TLP version of r17's fused kernel.
//  - r17 fact base: fused kb-loop needs only ~60 VGPR (no spills, WRITE
//    clean); W2-from-global (L1-resident bf16 image) cost nothing (0 bank
//    conflicts, best time 63.9us). Only LDS (33.8KB) capped occupancy at 39%.
//  - So: W1+b1 ALSO from the pre-converted global image; no __shared__, no
//    __syncthreads, no staging. Each wave fully independent. VGPR-only
//    residency cap -> up to 8 waves/SIMD (first time healthy codegen meets
//    high occupancy).
//  - kappa trick (r11/r15/r17-proven): W2 stored column-permuted by
//    kappa(f)=[t>>1|q|t&1|r]; GEMM2's B-fragment IS the gelu'd GEMM1 output.
//  - per kb: {W2 loads || GEMM1 2t x 2m MFMA || gelu || GEMM2 4dt x 2m MFMA}.
//  - R read in epilogue next to out-write (r13/r14 L3 lesson).
// 2048 blocks x 4 independent waves x 32 tokens.

typedef __attribute__((ext_vector_type(8))) short bf16x8;   // MFMA A/B frag
typedef __attribute__((ext_vector_type(4))) float f32x4;    // MFMA C/D frag
typedef __attribute__((ext_vector_type(4))) short short4v;  // packed 4x bf16

#define NBLK 2048    // 2048 blocks * 4 waves * 32 tokens = 262144

__device__ __forceinline__ short f2bf(float x) {
    union { __hip_bfloat16 h; short s; } u;
    u.h = __float2bfloat16(x);      // compiler pairs into v_cvt_pk_bf16_f32
    return u.s;
}

__device__ __forceinline__ float bloom_gelu(float x) {
    // 0.5*x*(1+tanh(0.79788456*(x+0.044715*x^3))) = x*(1 - 1/(e^{2u}+1))
    // 2u*log2(e) = 2.30220842*x + 0.10294325*x^3 -> v_exp_f32 (2^x) direct
    float x2 = x * x;
    float t1 = __builtin_fmaf(0.10294325f, x2, 2.30220842f);
    float e  = __builtin_exp2f(x * t1);
    float r  = __builtin_amdgcn_rcpf(e + 1.0f);
    return x - x * r;
}

// ---- pre-pass: ws image = [W1 linear bf16 32KB][W2 kappa-linear bf16 32KB]
// W2 col f bits: [7:4]=t [3:2]=q [1:0]=r -> kappa=[7:5]=t>>1 [4:3]=q [2]=t&1 [1:0]=r
__global__ __launch_bounds__(256) void cvt_weights(
    const float* __restrict__ W1, const float* __restrict__ W2,
    short* __restrict__ wsb)
{
    const int i4 = (blockIdx.x * 256 + threadIdx.x) * 4;   // 0..32764, step 4
    if (i4 < 16384) {
        float4 v = *(const float4*)(W1 + i4);
        short4v o;
        o[0]=f2bf(v.x); o[1]=f2bf(v.y); o[2]=f2bf(v.z); o[3]=f2bf(v.w);
        *(short4v*)(wsb + i4) = o;                         // linear W1
    } else {
        const int rel = i4 - 16384;
        const int d = rel >> 8, f = rel & 255;             // 4 f share t,q
        const int t = f >> 4, qq = (f >> 2) & 3;
        const int k4 = ((t >> 1) << 5) | (qq << 3) | ((t & 1) << 2);
        float4 v = *(const float4*)(W2 + rel);
        short4v o;
        o[0]=f2bf(v.x); o[1]=f2bf(v.y); o[2]=f2bf(v.z); o[3]=f2bf(v.w);
        *(short4v*)(wsb + 16384 + (d << 8) + k4) = o;      // kappa W2
    }
}

template<bool PRE>
__global__ __launch_bounds__(256, 4) void bloom_mlp(
    const float* __restrict__ X,  const float* __restrict__ R,
    const float* __restrict__ W1, const float* __restrict__ b1,
    const float* __restrict__ W2, const float* __restrict__ b2,
    const short* __restrict__ Wb, float* __restrict__ out)
{
    const int tid  = threadIdx.x;
    const int wid  = tid >> 6;      // wave 0..3 (fully independent)
    const int lane = tid & 63;
    const int q    = lane >> 4;     // 0..3
    const int c    = lane & 15;     // 0..15
    const int tok0 = blockIdx.x * 128 + wid * 32;

    // ---- X loads (8 float4/lane), issued up front ----
    float4 xr[2][4];
#pragma unroll
    for (int m = 0; m < 2; ++m) {
        const float* p = X + (size_t)(tok0 + 16*m + c) * 64 + q*8;
        xr[m][0] = *(const float4*)(p);
        xr[m][1] = *(const float4*)(p + 4);
        xr[m][2] = *(const float4*)(p + 32);
        xr[m][3] = *(const float4*)(p + 36);
    }
    bf16x8 a1[2][2];
#pragma unroll
    for (int m = 0; m < 2; ++m)
#pragma unroll
        for (int kb = 0; kb < 2; ++kb) {
            const float4 lo = xr[m][2*kb], hi = xr[m][2*kb+1];
            bf16x8 f;
            f[0]=f2bf(lo.x); f[1]=f2bf(lo.y); f[2]=f2bf(lo.z); f[3]=f2bf(lo.w);
            f[4]=f2bf(hi.x); f[5]=f2bf(hi.y); f[6]=f2bf(hi.z); f[7]=f2bf(hi.w);
            a1[m][kb] = f;
        }

    // ================= fused kb pipeline (no LDS, no barriers) =================
    f32x4 acc2[2][4] = {{{0,0,0,0},{0,0,0,0},{0,0,0,0},{0,0,0,0}},
                        {{0,0,0,0},{0,0,0,0},{0,0,0,0},{0,0,0,0}}};
#pragma unroll
    for (int kb = 0; kb < 8; ++kb) {
        // W2 fragments (kappa image, L1-resident), issued first
        bf16x8 w2f[4];
#pragma unroll
        for (int dt = 0; dt < 4; ++dt) {
            if constexpr (PRE) {
                w2f[dt] = *(const bf16x8*)&Wb[16384 + (16*dt + c) * 256 + kb*32 + q*8];
            } else {
                const float* p = W2 + (size_t)(16*dt + c) * 256 + kb*32 + 4*q;
                float4 lo = *(const float4*)p, hi = *(const float4*)(p + 16);
                bf16x8 f;
                f[0]=f2bf(lo.x); f[1]=f2bf(lo.y); f[2]=f2bf(lo.z); f[3]=f2bf(lo.w);
                f[4]=f2bf(hi.x); f[5]=f2bf(hi.y); f[6]=f2bf(hi.z); f[7]=f2bf(hi.w);
                w2f[dt] = f;
            }
        }

        // GEMM1 + gelu for the two t's feeding this kb
        bf16x8 pm[2];
#pragma unroll
        for (int tt = 0; tt < 2; ++tt) {
            const int t   = 2*kb + tt;
            const int row = 16*t + c;
            bf16x8 w1a, w1b;
            if constexpr (PRE) {
                w1a = *(const bf16x8*)&Wb[row * 64 + q*8];          // k 0..31
                w1b = *(const bf16x8*)&Wb[row * 64 + 32 + q*8];     // k 32..63
            } else {
                const float* p = W1 + (size_t)row * 64 + q*8;
                float4 lo = *(const float4*)p, hi = *(const float4*)(p + 4);
                bf16x8 f;
                f[0]=f2bf(lo.x); f[1]=f2bf(lo.y); f[2]=f2bf(lo.z); f[3]=f2bf(lo.w);
                f[4]=f2bf(hi.x); f[5]=f2bf(hi.y); f[6]=f2bf(hi.z); f[7]=f2bf(hi.w);
                w1a = f;
                lo = *(const float4*)(p + 32); hi = *(const float4*)(p + 36);
                f[0]=f2bf(lo.x); f[1]=f2bf(lo.y); f[2]=f2bf(lo.z); f[3]=f2bf(lo.w);
                f[4]=f2bf(hi.x); f[5]=f2bf(hi.y); f[6]=f2bf(hi.z); f[7]=f2bf(hi.w);
                w1b = f;
            }
            const float4 b1v = *(const float4*)(b1 + 16*t + 4*q);
#pragma unroll
            for (int m = 0; m < 2; ++m) {
                f32x4 acc = {0.f, 0.f, 0.f, 0.f};
                acc = __builtin_amdgcn_mfma_f32_16x16x32_bf16(w1a, a1[m][0], acc, 0, 0, 0);
                acc = __builtin_amdgcn_mfma_f32_16x16x32_bf16(w1b, a1[m][1], acc, 0, 0, 0);
                // D[f=16t+4q+r][token=c] -> kappa slot pm[m][tt*4+r]
#pragma unroll
                for (int r = 0; r < 4; ++r)
                    pm[m][(tt << 2) + r] = f2bf(bloom_gelu(acc[r] + b1v[r]));
            }
        }

        // GEMM2: consume pm immediately (kappa: pm IS the B-fragment)
#pragma unroll
        for (int dt = 0; dt < 4; ++dt)
#pragma unroll
            for (int m = 0; m < 2; ++m)
                acc2[m][dt] = __builtin_amdgcn_mfma_f32_16x16x32_bf16(
                    w2f[dt], pm[m], acc2[m][dt], 0, 0, 0);
    }

    // ---- epilogue: D[d=16dt+4q+r][token=c]; R read next to out-write ----
#pragma unroll
    for (int m = 0; m < 2; ++m)
#pragma unroll
        for (int dt = 0; dt < 4; ++dt) {
            const size_t off = (size_t)(tok0 + 16*m + c) * 64 + 16*dt + 4*q;
            const float4 r4  = *(const float4*)(R + off);
            const float4 b2v = *(const float4*)(b2 + 16*dt + 4*q);
            float4 o;
            o.x = acc2[m][dt][0] + b2v.x + r4.x;
            o.y = acc2[m][dt][1] + b2v.y + r4.y;
            o.z = acc2[m][dt][2] + b2v.z + r4.z;
            o.w = acc2[m][dt][3] + b2v.w + r4.w;
            *(float4*)(out + off) = o;
        }
}

extern "C" void kernel_launch(void* const* d_in, const int* in_sizes, int n_in,
                              void* d_out, int out_size, void* d_ws, size_t ws_size,
                              hipStream_t stream) {
    const float* X  = (const float*)d_in[0];
    const float* R  = (const float*)d_in[1];
    const float* W1 = (const float*)d_in[2];
    const float* b1 = (const float*)d_in[3];
    const float* W2 = (const float*)d_in[4];
    const float* b2 = (const float*)d_in[5];
    float* out = (float*)d_out;
    (void)in_sizes; (void)n_in; (void)out_size;

    if (ws_size >= 65536) {
        short* wsb = (short*)d_ws;
        cvt_weights<<<32, 256, 0, stream>>>(W1, W2, wsb);
        bloom_mlp<true><<<NBLK, 256, 0, stream>>>(X, R, W1, b1, W2, b2, wsb, out);
    } else {
        bloom_mlp<false><<<NBLK, 256, 0, stream>>>(X, R, W1, b1, W2, b2, nullptr, out);
    }
}

// Round 20
// 63.635 us; speedup vs baseline: 1.4726x; 1.4726x over previous
//
#include <hip/hip_runtime.h>
#include <hip/hip_bf16.h>

// Bloom MLP fused: h=X@W1^T+b1; g=gelu_tanh(h); out=g@W2^T+b2+residual
// X:[262144,64] f32, W1:[256,64], W2:[64,256], out:[262144,64] f32.
//
// Round 20 = round 17 (best, 63.9us) + nontemporal out-stores, type-fixed:
// r19's __builtin_nontemporal_store rejected HIP float4 (class type); use a
// native ext_vector_type(4) float alias for the store. Hypothesis unchanged:
// warm replays still fetch 66MB because the 67MB out-write stream allocates
// in L3 and evicts X/R; nt stores keep out out of L3 -> X+R (134MB) stay
// L3-resident -> warm FETCH collapses. Everything else bit-identical to r17:
//  - kappa-permuted W2 from global (32KB bf16 image, L1-resident), W1+b1 in
//    LDS (33KB -> 4 blocks/CU), fused kb-loop (~60 VGPR), ONE barrier, (256,4).

typedef __attribute__((ext_vector_type(8))) short bf16x8;   // MFMA A/B frag
typedef __attribute__((ext_vector_type(4))) float f32x4;    // MFMA C/D frag
typedef __attribute__((ext_vector_type(4))) float f32x4v;   // nt-store vector
typedef __attribute__((ext_vector_type(4))) short short4v;  // packed 4x bf16

#define NBLK 2048    // 2048 blocks * 4 waves * 32 tokens = 262144

__device__ __forceinline__ short f2bf(float x) {
    union { __hip_bfloat16 h; short s; } u;
    u.h = __float2bfloat16(x);      // compiler pairs into v_cvt_pk_bf16_f32
    return u.s;
}

__device__ __forceinline__ float bloom_gelu(float x) {
    // 0.5*x*(1+tanh(0.79788456*(x+0.044715*x^3))) = x*(1 - 1/(e^{2u}+1))
    // 2u*log2(e) = 2.30220842*x + 0.10294325*x^3 -> v_exp_f32 (2^x) direct
    float x2 = x * x;
    float t1 = __builtin_fmaf(0.10294325f, x2, 2.30220842f);
    float e  = __builtin_exp2f(x * t1);
    float r  = __builtin_amdgcn_rcpf(e + 1.0f);
    return x - x * r;
}

// W1 LDS image: [256 rows][64 shorts], 8 slots of 8 shorts per row,
// slot XOR-swizzled by row&7.
__device__ __forceinline__ int w1_off(int row, int slot) {
    return row * 64 + ((slot ^ (row & 7)) << 3);
}

// async global->LDS, 16B per lane; dest lane-linear (base+lane*16)
__device__ __forceinline__ void gload_lds16(const void* src, void* dst) {
    __builtin_amdgcn_global_load_lds(
        (const __attribute__((address_space(1))) void*)src,
        (__attribute__((address_space(3))) void*)dst, 16, 0, 0);
}

// ---- pre-pass: ws image = [W1 swizzled bf16 32KB][W2 kappa-linear bf16 32KB]
// W2 col f bits: [7:4]=t [3:2]=q [1:0]=r -> kappa=[7:5]=t>>1 [4:3]=q [2]=t&1 [1:0]=r
__global__ __launch_bounds__(256) void cvt_weights(
    const float* __restrict__ W1, const float* __restrict__ W2,
    short* __restrict__ wsb)
{
    const int i4 = (blockIdx.x * 256 + threadIdx.x) * 4;   // 0..32764, step 4
    if (i4 < 16384) {
        const int row = i4 >> 6, col = i4 & 63;
        float4 v = *(const float4*)(W1 + i4);
        short4v o;
        o[0]=f2bf(v.x); o[1]=f2bf(v.y); o[2]=f2bf(v.z); o[3]=f2bf(v.w);
        *(short4v*)(wsb + w1_off(row, col >> 3) + (col & 7)) = o;
    } else {
        const int rel = i4 - 16384;
        const int d = rel >> 8, f = rel & 255;             // 4 f share t,q
        const int t = f >> 4, qq = (f >> 2) & 3;
        const int k4 = ((t >> 1) << 5) | (qq << 3) | ((t & 1) << 2);
        float4 v = *(const float4*)(W2 + rel);
        short4v o;
        o[0]=f2bf(v.x); o[1]=f2bf(v.y); o[2]=f2bf(v.z); o[3]=f2bf(v.w);
        *(short4v*)(wsb + 16384 + (d << 8) + k4) = o;      // linear kappa
    }
}

template<bool PRE>
__global__ __launch_bounds__(256, 4) void bloom_mlp(
    const float* __restrict__ X,  const float* __restrict__ R,
    const float* __restrict__ W1, const float* __restrict__ b1,
    const float* __restrict__ W2, const float* __restrict__ b2,
    const short* __restrict__ Wb, float* __restrict__ out)
{
    __shared__ __align__(16) short W1lds[16384];   // 32 KB swizzled W1
    __shared__ __align__(16) float Bl1[256];       //  1 KB b1

    const int tid  = threadIdx.x;
    const int wid  = tid >> 6;      // wave 0..3 (independent after the barrier)
    const int lane = tid & 63;
    const int q    = lane >> 4;     // 0..3
    const int c    = lane & 15;     // 0..15
    const int tok0 = blockIdx.x * 128 + wid * 32;

    // ---- issue X now (8 float4/lane): flies across weight staging ----
    float4 xr[2][4];
#pragma unroll
    for (int m = 0; m < 2; ++m) {
        const float* p = X + (size_t)(tok0 + 16*m + c) * 64 + q*8;
        xr[m][0] = *(const float4*)(p);
        xr[m][1] = *(const float4*)(p + 4);
        xr[m][2] = *(const float4*)(p + 32);
        xr[m][3] = *(const float4*)(p + 36);
    }

    // ---- stage W1 (32KB) + b1 (1KB) into LDS ----
    if constexpr (PRE) {
#pragma unroll
        for (int k = 0; k < 8; ++k) {
            const int s8 = (k * 256 + tid) * 8;            // short index
            gload_lds16(Wb + s8, &W1lds[s8]);
        }
        if (tid < 64) gload_lds16(b1 + tid * 4, &Bl1[tid * 4]);
    } else {
#pragma unroll
        for (int k = 0; k < 16; ++k) {
            const int i4 = (k * 256 + tid) * 4;            // W1 floats
            const int row = i4 >> 6, col = i4 & 63;
            float4 v = *(const float4*)(W1 + i4);
            short4v o;
            o[0]=f2bf(v.x); o[1]=f2bf(v.y); o[2]=f2bf(v.z); o[3]=f2bf(v.w);
            *(short4v*)&W1lds[w1_off(row, col >> 3) + (col & 7)] = o;
        }
        if (tid < 64) *(float4*)&Bl1[tid * 4] = *(const float4*)(b1 + tid * 4);
    }

    // X -> bf16 fragments (lane holds X[tok0+16m+c][kb*32+q*8..+7])
    bf16x8 a1[2][2];
#pragma unroll
    for (int m = 0; m < 2; ++m)
#pragma unroll
        for (int kb = 0; kb < 2; ++kb) {
            const float4 lo = xr[m][2*kb], hi = xr[m][2*kb+1];
            bf16x8 f;
            f[0]=f2bf(lo.x); f[1]=f2bf(lo.y); f[2]=f2bf(lo.z); f[3]=f2bf(lo.w);
            f[4]=f2bf(hi.x); f[5]=f2bf(hi.y); f[6]=f2bf(hi.z); f[7]=f2bf(hi.w);
            a1[m][kb] = f;
        }

    __syncthreads();   // THE one barrier: W1/b1 staged (drains vm+lgkm)

    // ================= fused kb pipeline (zero-sync) =================
    f32x4 acc2[2][4] = {{{0,0,0,0},{0,0,0,0},{0,0,0,0},{0,0,0,0}},
                        {{0,0,0,0},{0,0,0,0},{0,0,0,0},{0,0,0,0}}};
#pragma unroll
    for (int kb = 0; kb < 8; ++kb) {
        // W2 fragments from global (L1-resident image), issued first
        bf16x8 w2f[4];
#pragma unroll
        for (int dt = 0; dt < 4; ++dt) {
            if constexpr (PRE) {
                w2f[dt] = *(const bf16x8*)&Wb[16384 + (16*dt + c) * 256 + kb*32 + q*8];
            } else {
                const float* p = W2 + (size_t)(16*dt + c) * 256 + kb*32 + 4*q;
                float4 lo = *(const float4*)p, hi = *(const float4*)(p + 16);
                bf16x8 f;
                f[0]=f2bf(lo.x); f[1]=f2bf(lo.y); f[2]=f2bf(lo.z); f[3]=f2bf(lo.w);
                f[4]=f2bf(hi.x); f[5]=f2bf(hi.y); f[6]=f2bf(hi.z); f[7]=f2bf(hi.w);
                w2f[dt] = f;
            }
        }

        // GEMM1 + gelu for the two t's feeding this kb
        bf16x8 pm[2];
#pragma unroll
        for (int tt = 0; tt < 2; ++tt) {
            const int t   = 2*kb + tt;
            const int row = 16*t + c;
            const bf16x8 w1a = *(const bf16x8*)&W1lds[w1_off(row, q)];      // k 0..31
            const bf16x8 w1b = *(const bf16x8*)&W1lds[w1_off(row, 4 + q)];  // k 32..63
            const float4 b1v = *(const float4*)&Bl1[16*t + 4*q];
#pragma unroll
            for (int m = 0; m < 2; ++m) {
                f32x4 acc = {0.f, 0.f, 0.f, 0.f};
                acc = __builtin_amdgcn_mfma_f32_16x16x32_bf16(w1a, a1[m][0], acc, 0, 0, 0);
                acc = __builtin_amdgcn_mfma_f32_16x16x32_bf16(w1b, a1[m][1], acc, 0, 0, 0);
                // D[f=16t+4q+r][token=c] -> kappa slot pm[m][tt*4+r]
#pragma unroll
                for (int r = 0; r < 4; ++r)
                    pm[m][(tt << 2) + r] = f2bf(bloom_gelu(acc[r] + b1v[r]));
            }
        }

        // GEMM2: consume pm immediately (kappa: pm IS the B-fragment)
#pragma unroll
        for (int dt = 0; dt < 4; ++dt)
#pragma unroll
            for (int m = 0; m < 2; ++m)
                acc2[m][dt] = __builtin_amdgcn_mfma_f32_16x16x32_bf16(
                    w2f[dt], pm[m], acc2[m][dt], 0, 0, 0);
    }

    // ---- epilogue: D[d=16dt+4q+r][token=c]; R read next to out-write;
    //      out stored NONTEMPORAL (ext-vector type: legal for the builtin) ----
#pragma unroll
    for (int m = 0; m < 2; ++m)
#pragma unroll
        for (int dt = 0; dt < 4; ++dt) {
            const size_t off = (size_t)(tok0 + 16*m + c) * 64 + 16*dt + 4*q;
            const float4 r4  = *(const float4*)(R + off);
            const float4 b2v = *(const float4*)(b2 + 16*dt + 4*q);
            f32x4v o;
            o[0] = acc2[m][dt][0] + b2v.x + r4.x;
            o[1] = acc2[m][dt][1] + b2v.y + r4.y;
            o[2] = acc2[m][dt][2] + b2v.z + r4.z;
            o[3] = acc2[m][dt][3] + b2v.w + r4.w;
            __builtin_nontemporal_store(o, (f32x4v*)(out + off));
        }
}

extern "C" void kernel_launch(void* const* d_in, const int* in_sizes, int n_in,
                              void* d_out, int out_size, void* d_ws, size_t ws_size,
                              hipStream_t stream) {
    const float* X  = (const float*)d_in[0];
    const float* R  = (const float*)d_in[1];
    const float* W1 = (const float*)d_in[2];
    const float* b1 = (const float*)d_in[3];
    const float* W2 = (const float*)d_in[4];
    const float* b2 = (const float*)d_in[5];
    float* out = (float*)d_out;
    (void)in_sizes; (void)n_in; (void)out_size;

    if (ws_size >= 65536) {
        short* wsb = (short*)d_ws;
        cvt_weights<<<32, 256, 0, stream>>>(W1, W2, wsb);
        bloom_mlp<true><<<NBLK, 256, 0, stream>>>(X, R, W1, b1, W2, b2, wsb, out);
    } else {
        bloom_mlp<false><<<NBLK, 256, 0, stream>>>(X, R, W1, b1, W2, b2, nullptr, out);
    }
}